// Round 1
// baseline (444.360 us; speedup 1.0000x reference)
//
#include <hip/hip_runtime.h>

#define IN_CH 3
#define OUT_CH 32
#define KK 3
#define IN_FEAT 27
#define NB 5      // N_BASIS
#define NG 8      // grid knots
#define HH 256
#define WW 256
#define NPIX (16 * HH * WW)

// ---------------------------------------------------------------------------
// Kernel 1: combine weights into Wc[f][6][32]:
//   j==0 -> base_weight[o][f]
//   j>=1 -> spline_weight[o][f][j-1] * spline_scaler[o][f]
// ---------------------------------------------------------------------------
__global__ void kan_combine_weights(const float* __restrict__ bw,
                                    const float* __restrict__ sw,
                                    const float* __restrict__ ss,
                                    float* __restrict__ wc) {
    int idx = blockIdx.x * blockDim.x + threadIdx.x;
    if (idx >= IN_FEAT * 6 * OUT_CH) return;
    int o = idx & 31;
    int j = (idx >> 5) % 6;
    int f = idx / (6 * 32);
    float v;
    if (j == 0) v = bw[o * IN_FEAT + f];
    else        v = sw[(o * IN_FEAT + f) * NB + (j - 1)] * ss[o * IN_FEAT + f];
    wc[idx] = v;
}

// ---------------------------------------------------------------------------
// Main kernel: one thread per output pixel; 32 fp32 accumulators.
// Weights read with wave-uniform indices -> scalar loads (K$), FMA v,s,v.
// ---------------------------------------------------------------------------
__global__ __launch_bounds__(256) void kan_main(const float* __restrict__ x,
                                                const float* __restrict__ grid,
                                                const float* __restrict__ wc,
                                                float* __restrict__ out) {
    const int p = blockIdx.x * blockDim.x + threadIdx.x;
    const int w = p & (WW - 1);
    const int h = (p >> 8) & (HH - 1);
    const int b = p >> 16;

    // grid knots (row 0 of (27,8); all rows identical) -- uniform -> SGPRs
    float g[NG];
#pragma unroll
    for (int j = 0; j < NG; ++j) g[j] = grid[j];
    // reciprocal denominators (uniform)
    float r1[NG - 1];
#pragma unroll
    for (int j = 0; j < NG - 1; ++j) r1[j] = 1.0f / (g[j + 1] - g[j]);
    float r2[NG - 2];
#pragma unroll
    for (int j = 0; j < NG - 2; ++j) r2[j] = 1.0f / (g[j + 2] - g[j]);

    float acc[OUT_CH];
#pragma unroll
    for (int o = 0; o < OUT_CH; ++o) acc[o] = 0.0f;

    const float* xb = x + b * (IN_CH * HH * WW);

    for (int c = 0; c < IN_CH; ++c) {
        const float* xc = xb + c * (HH * WW);
#pragma unroll
        for (int dy = 0; dy < KK; ++dy) {
            const int hy = h + dy - 1;
            const bool vy = (hy >= 0) && (hy < HH);
#pragma unroll
            for (int dx = 0; dx < KK; ++dx) {
                const int wx = w + dx - 1;
                const bool vld = vy && (wx >= 0) && (wx < WW);
                const float xx = vld ? xc[hy * WW + wx] : 0.0f;

                // silu
                const float sig = 1.0f / (1.0f + __expf(-xx));
                const float a0 = xx * sig;

                // B-spline bases: order 0 (indicators), then Cox-de Boor
                float b0[7];
#pragma unroll
                for (int j = 0; j < 7; ++j)
                    b0[j] = (xx >= g[j] && xx < g[j + 1]) ? 1.0f : 0.0f;
                float b1[6];
#pragma unroll
                for (int j = 0; j < 6; ++j)
                    b1[j] = (xx - g[j]) * r1[j] * b0[j]
                          + (g[j + 2] - xx) * r1[j + 1] * b0[j + 1];
                float b2[NB];
#pragma unroll
                for (int j = 0; j < NB; ++j)
                    b2[j] = (xx - g[j]) * r2[j] * b1[j]
                          + (g[j + 3] - xx) * r2[j + 1] * b1[j + 1];

                // contract against combined weights (uniform index -> s_load)
                const float* wf = wc + (c * 9 + dy * 3 + dx) * (6 * OUT_CH);
#pragma unroll
                for (int o = 0; o < OUT_CH; ++o) acc[o] += a0 * wf[o];
#pragma unroll
                for (int jj = 0; jj < NB; ++jj) {
                    const float* wj = wf + (jj + 1) * OUT_CH;
#pragma unroll
                    for (int o = 0; o < OUT_CH; ++o) acc[o] += b2[jj] * wj[o];
                }
            }
        }
    }

    float* ob = out + b * (OUT_CH * HH * WW) + h * WW + w;
#pragma unroll
    for (int o = 0; o < OUT_CH; ++o) ob[o * (HH * WW)] = acc[o];
}

// ---------------------------------------------------------------------------
extern "C" void kernel_launch(void* const* d_in, const int* in_sizes, int n_in,
                              void* d_out, int out_size, void* d_ws, size_t ws_size,
                              hipStream_t stream) {
    const float* x    = (const float*)d_in[0];
    const float* bw   = (const float*)d_in[1];
    const float* sw   = (const float*)d_in[2];
    const float* ss   = (const float*)d_in[3];
    const float* grid = (const float*)d_in[4];
    float* out = (float*)d_out;
    float* wc  = (float*)d_ws;   // 27*6*32 floats = 20736 B

    kan_combine_weights<<<(IN_FEAT * 6 * OUT_CH + 255) / 256, 256, 0, stream>>>(bw, sw, ss, wc);
    kan_main<<<NPIX / 256, 256, 0, stream>>>(x, grid, wc, out);
}

// Round 4
// 80.369 us; speedup vs baseline: 5.5290x; 5.5290x over previous
//
#include <hip/hip_runtime.h>

#define IN_CH 3
#define OUT_CH 32
#define IN_FEAT 27
#define NB 5
#define NG 8
#define HH 256
#define WW 256
#define NPIX (16 * HH * WW)

// Phi record: 24 fp16 = 48 bytes. order: c*6 + j, elems 18..23 = 0
#define RECE 24
#define WB_HALVES (9 * 2 * 64 * 8)      // 9216 halves = 18432 B
#define PHI0_OFF WB_HALVES              // phi(0) record lives right after wb
#define PHI_OFF_BYTES 32768
#define WS_NEEDED (PHI_OFF_BYTES + (size_t)NPIX * RECE * 2)

typedef __attribute__((ext_vector_type(8))) _Float16 half8;
typedef __attribute__((ext_vector_type(4))) float f32x4;
typedef __attribute__((ext_vector_type(4))) unsigned int u32x4;

// silu + quadratic B-spline bases (exact Cox-de Boor per reference)
__device__ inline void kan_phi6(float xx, const float* g, const float* r1, const float* r2,
                                float* o6) {
    const float sig = 1.0f / (1.0f + __expf(-xx));
    o6[0] = xx * sig;
    float b0[7];
#pragma unroll
    for (int j = 0; j < 7; ++j) b0[j] = (xx >= g[j] && xx < g[j + 1]) ? 1.0f : 0.0f;
    float b1[6];
#pragma unroll
    for (int j = 0; j < 6; ++j)
        b1[j] = (xx - g[j]) * r1[j] * b0[j] + (g[j + 2] - xx) * r1[j + 1] * b0[j + 1];
#pragma unroll
    for (int j = 0; j < NB; ++j)
        o6[1 + j] = (xx - g[j]) * r2[j] * b1[j] + (g[j + 3] - xx) * r2[j + 1] * b1[j + 1];
}

__device__ inline void load_grid(const float* __restrict__ grid, float* g, float* r1, float* r2) {
#pragma unroll
    for (int j = 0; j < NG; ++j) g[j] = grid[j];
#pragma unroll
    for (int j = 0; j < NG - 1; ++j) r1[j] = 1.0f / (g[j + 1] - g[j]);
#pragma unroll
    for (int j = 0; j < NG - 2; ++j) r2[j] = 1.0f / (g[j + 2] - g[j]);
}

// ---------------------------------------------------------------------------
// Prep: weights -> exact B-fragment layout (fp16). wb[((tap*2+nt)*64+lane)*8+e]
//   per-tap k = (lane>>4)*8 + e ; real if k<18: c=k/6, j=k%6, f=c*9+tap
//   col n = lane&15 ; o = nt*16 + n
// Thread 0 additionally writes the phi(0) record (for padded taps) at
// wb + PHI0_OFF: reference pads patches with 0, and bases(0) != 0.
// ---------------------------------------------------------------------------
__global__ void kan_prepW(const float* __restrict__ bw, const float* __restrict__ sw,
                          const float* __restrict__ ss, const float* __restrict__ grid,
                          _Float16* __restrict__ wb) {
    int t = blockIdx.x * 256 + threadIdx.x;
    if (t >= 9 * 2 * 64) return;

    if (t == 0) {
        float g[NG], r1[NG - 1], r2[NG - 2];
        load_grid(grid, g, r1, r2);
        float o6[6];
        kan_phi6(0.0f, g, r1, r2, o6);
        _Float16* p0 = wb + PHI0_OFF;
#pragma unroll
        for (int c = 0; c < IN_CH; ++c)
#pragma unroll
            for (int j = 0; j < 6; ++j) p0[c * 6 + j] = (_Float16)o6[j];
#pragma unroll
        for (int j = 18; j < RECE; ++j) p0[j] = (_Float16)0.0f;
    }

    const int lane = t & 63;
    const int nt = (t >> 6) & 1;
    const int tap = t >> 7;
    const int o = nt * 16 + (lane & 15);
    const int kbase = (lane >> 4) * 8;
    half8 v8 = {0, 0, 0, 0, 0, 0, 0, 0};
#pragma unroll
    for (int e = 0; e < 8; ++e) {
        int kk = kbase + e;
        float v = 0.0f;
        if (kk < 18) {
            int c = kk / 6, j = kk % 6;
            int f = c * 9 + tap;
            int of = o * IN_FEAT + f;
            v = (j == 0) ? bw[of] : sw[of * NB + (j - 1)] * ss[of];
        }
        v8[e] = (_Float16)v;
    }
    *(half8*)(wb + (size_t)t * 8) = v8;
}

// ---------------------------------------------------------------------------
// Stage A: per input spatial pixel, compute phi for all 3 channels -> 24 fp16
// ---------------------------------------------------------------------------
__global__ __launch_bounds__(256) void kan_stageA(const float* __restrict__ x,
                                                  const float* __restrict__ grid,
                                                  _Float16* __restrict__ phi) {
    const int p = blockIdx.x * 256 + threadIdx.x;
    const int w = p & (WW - 1);
    const int h = (p >> 8) & (HH - 1);
    const int b = p >> 16;

    float g[NG], r1[NG - 1], r2[NG - 2];
    load_grid(grid, g, r1, r2);

    _Float16 rec[RECE];
#pragma unroll
    for (int c = 0; c < IN_CH; ++c) {
        const float xx = x[((b * IN_CH + c) << 16) + (h << 8) + w];
        float o6[6];
        kan_phi6(xx, g, r1, r2, o6);
#pragma unroll
        for (int j = 0; j < 6; ++j) rec[c * 6 + j] = (_Float16)o6[j];
    }
#pragma unroll
    for (int j = 18; j < RECE; ++j) rec[j] = (_Float16)0.0f;

    half8* dst = (half8*)(phi + (size_t)p * RECE);
    dst[0] = *(half8*)(rec + 0);
    dst[1] = *(half8*)(rec + 8);
    dst[2] = *(half8*)(rec + 16);
}

// ---------------------------------------------------------------------------
// Stage B: MFMA GEMM. Block = 256 thr = 4 waves = 64 consecutive pixels x 32 ch.
// Wave: M-tile 16 pixels; 9 taps (K=32 each, 18 real) x 2 N-tiles -> 18 MFMA.
// Out-of-bounds taps read the phi(0) record (reference zero-pads BEFORE phi).
// ---------------------------------------------------------------------------
__global__ __launch_bounds__(256) void kan_stageB(const _Float16* __restrict__ phi,
                                                  const _Float16* __restrict__ wb,
                                                  float* __restrict__ out) {
    __shared__ _Float16 lW[WB_HALVES];          // 18432 B, B-fragments
    __shared__ float lO[64 * 33];               // 8448 B, transpose buffer

    const int tid = threadIdx.x;
    for (int i = tid; i < WB_HALVES / 8; i += 256)
        ((u32x4*)lW)[i] = ((const u32x4*)wb)[i];
    __syncthreads();

    const int lane = tid & 63;
    const int wid = tid >> 6;
    const int p0 = blockIdx.x * 64;
    const int b = p0 >> 16;
    const int h = (p0 >> 8) & (HH - 1);
    const int w0 = p0 & (WW - 1);

    const int r = lane & 15;       // A row / B col within tile
    const int gq = lane >> 4;      // lane quarter: k-group
    const int wpix = w0 + wid * 16 + r;   // this lane's pixel w-coordinate

    const _Float16* phi0 = wb + PHI0_OFF;

    half8 af[9];
#pragma unroll
    for (int dy = 0; dy < 3; ++dy) {
        const int hy = h + dy - 1;
        const bool vy = (hy >= 0) && (hy < HH);
#pragma unroll
        for (int dx = 0; dx < 3; ++dx) {
            const int tap = dy * 3 + dx;
            const int wx = wpix + dx - 1;
            half8 v = {0, 0, 0, 0, 0, 0, 0, 0};
            if (gq < 3) {
                const _Float16* rp = phi0 + gq * 8;
                if (vy && (wx >= 0) && (wx < WW))
                    rp = phi + ((size_t)(((b << 8) + hy) << 8) + wx) * RECE + gq * 8;
                v = *(const half8*)rp;
            }
            af[tap] = v;
        }
    }

    f32x4 acc0 = {0.f, 0.f, 0.f, 0.f};
    f32x4 acc1 = {0.f, 0.f, 0.f, 0.f};
    const half8* lw8 = (const half8*)lW;
#pragma unroll
    for (int tap = 0; tap < 9; ++tap) {
        half8 bf0 = lw8[(tap * 2 + 0) * 64 + lane];
        half8 bf1 = lw8[(tap * 2 + 1) * 64 + lane];
        acc0 = __builtin_amdgcn_mfma_f32_16x16x32_f16(af[tap], bf0, acc0, 0, 0, 0);
        acc1 = __builtin_amdgcn_mfma_f32_16x16x32_f16(af[tap], bf1, acc1, 0, 0, 0);
    }

    // write acc -> lO[pix][33] ; pix = wid*16 + gq*4 + i ; ch = nt*16 + r
#pragma unroll
    for (int i = 0; i < 4; ++i) {
        lO[(wid * 16 + gq * 4 + i) * 33 + r] = acc0[i];
        lO[(wid * 16 + gq * 4 + i) * 33 + 16 + r] = acc1[i];
    }
    __syncthreads();

    // coalesced store: thread t: o = t>>3, pixel-group = (t&7)*8
    const int o = tid >> 3;
    const int ps = (tid & 7) * 8;
    float v[8];
#pragma unroll
    for (int i = 0; i < 8; ++i) v[i] = lO[(ps + i) * 33 + o];
    float* op = out + (((size_t)(b * OUT_CH + o) << 8) + h) * WW + w0 + ps;
    *(f32x4*)op       = (f32x4){v[0], v[1], v[2], v[3]};
    *(f32x4*)(op + 4) = (f32x4){v[4], v[5], v[6], v[7]};
}

// ===========================================================================
// Fallback (round-1 fp32 path) if ws_size is too small for Phi
// ===========================================================================
__global__ void kan_combine_weights(const float* __restrict__ bw,
                                    const float* __restrict__ sw,
                                    const float* __restrict__ ss,
                                    float* __restrict__ wc) {
    int idx = blockIdx.x * blockDim.x + threadIdx.x;
    if (idx >= IN_FEAT * 6 * OUT_CH) return;
    int o = idx & 31;
    int j = (idx >> 5) % 6;
    int f = idx / (6 * 32);
    float v;
    if (j == 0) v = bw[o * IN_FEAT + f];
    else        v = sw[(o * IN_FEAT + f) * NB + (j - 1)] * ss[o * IN_FEAT + f];
    wc[idx] = v;
}

__global__ __launch_bounds__(256) void kan_main(const float* __restrict__ x,
                                                const float* __restrict__ grid,
                                                const float* __restrict__ wc,
                                                float* __restrict__ out) {
    const int p = blockIdx.x * blockDim.x + threadIdx.x;
    const int w = p & (WW - 1);
    const int h = (p >> 8) & (HH - 1);
    const int b = p >> 16;
    float g[NG], r1[NG - 1], r2[NG - 2];
    load_grid(grid, g, r1, r2);
    float acc[OUT_CH];
#pragma unroll
    for (int o = 0; o < OUT_CH; ++o) acc[o] = 0.0f;
    const float* xb = x + b * (IN_CH * HH * WW);
    for (int c = 0; c < IN_CH; ++c) {
        const float* xc = xb + c * (HH * WW);
#pragma unroll
        for (int dy = 0; dy < 3; ++dy) {
            const int hy = h + dy - 1;
            const bool vy = (hy >= 0) && (hy < HH);
#pragma unroll
            for (int dx = 0; dx < 3; ++dx) {
                const int wx = w + dx - 1;
                const bool vld = vy && (wx >= 0) && (wx < WW);
                const float xx = vld ? xc[hy * WW + wx] : 0.0f;
                float o6[6];
                kan_phi6(xx, g, r1, r2, o6);
                const float* wf = wc + (c * 9 + dy * 3 + dx) * (6 * OUT_CH);
#pragma unroll
                for (int jj = 0; jj < 6; ++jj) {
                    const float* wj = wf + jj * OUT_CH;
#pragma unroll
                    for (int o = 0; o < OUT_CH; ++o) acc[o] += o6[jj] * wj[o];
                }
            }
        }
    }
    float* ob = out + (size_t)b * (OUT_CH * HH * WW) + h * WW + w;
#pragma unroll
    for (int o = 0; o < OUT_CH; ++o) ob[o * (HH * WW)] = acc[o];
}

// ===========================================================================
extern "C" void kernel_launch(void* const* d_in, const int* in_sizes, int n_in,
                              void* d_out, int out_size, void* d_ws, size_t ws_size,
                              hipStream_t stream) {
    const float* x    = (const float*)d_in[0];
    const float* bw   = (const float*)d_in[1];
    const float* sw   = (const float*)d_in[2];
    const float* ss   = (const float*)d_in[3];
    const float* grid = (const float*)d_in[4];
    float* out = (float*)d_out;

    if (ws_size >= WS_NEEDED) {
        _Float16* wb  = (_Float16*)d_ws;
        _Float16* phi = (_Float16*)((char*)d_ws + PHI_OFF_BYTES);
        kan_prepW<<<(9 * 2 * 64 + 255) / 256, 256, 0, stream>>>(bw, sw, ss, grid, wb);
        kan_stageA<<<NPIX / 256, 256, 0, stream>>>(x, grid, phi);
        kan_stageB<<<NPIX / 64, 256, 0, stream>>>(phi, wb, out);
    } else {
        float* wc = (float*)d_ws;
        kan_combine_weights<<<(IN_FEAT * 6 * OUT_CH + 255) / 256, 256, 0, stream>>>(bw, sw, ss, wc);
        kan_main<<<NPIX / 256, 256, 0, stream>>>(x, grid, wc, out);
    }
}

// Round 5
// 71.976 us; speedup vs baseline: 6.1737x; 1.1166x over previous
//
#include <hip/hip_runtime.h>

#define IN_CH 3
#define OUT_CH 32
#define IN_FEAT 27
#define NB 5
#define NG 8
#define HH 256
#define WW 256
#define NPIX (16 * HH * WW)

// Phi record: 24 fp16 = 48 bytes. order: c*6 + j, elems 18..23 = 0
#define RECE 24
#define TW 66                            // halo tile width (64 + 2)
#define NREC (3 * TW)                    // 198 records per block
#define WB_HALVES (9 * 2 * 64 * 8)       // 9216 halves = 18432 B
#define WS_NEEDED ((size_t)WB_HALVES * 2)

typedef __attribute__((ext_vector_type(8))) _Float16 half8;
typedef __attribute__((ext_vector_type(4))) float f32x4;
typedef __attribute__((ext_vector_type(4))) unsigned int u32x4;

// silu + quadratic B-spline bases (exact Cox-de Boor per reference)
__device__ inline void kan_phi6(float xx, const float* g, const float* r1, const float* r2,
                                float* o6) {
    const float sig = 1.0f / (1.0f + __expf(-xx));
    o6[0] = xx * sig;
    float b0[7];
#pragma unroll
    for (int j = 0; j < 7; ++j) b0[j] = (xx >= g[j] && xx < g[j + 1]) ? 1.0f : 0.0f;
    float b1[6];
#pragma unroll
    for (int j = 0; j < 6; ++j)
        b1[j] = (xx - g[j]) * r1[j] * b0[j] + (g[j + 2] - xx) * r1[j + 1] * b0[j + 1];
#pragma unroll
    for (int j = 0; j < NB; ++j)
        o6[1 + j] = (xx - g[j]) * r2[j] * b1[j] + (g[j + 3] - xx) * r2[j + 1] * b1[j + 1];
}

__device__ inline void load_grid(const float* __restrict__ grid, float* g, float* r1, float* r2) {
#pragma unroll
    for (int j = 0; j < NG; ++j) g[j] = grid[j];
#pragma unroll
    for (int j = 0; j < NG - 1; ++j) r1[j] = 1.0f / (g[j + 1] - g[j]);
#pragma unroll
    for (int j = 0; j < NG - 2; ++j) r2[j] = 1.0f / (g[j + 2] - g[j]);
}

// ---------------------------------------------------------------------------
// Prep: weights -> exact B-fragment layout (fp16). wb[((tap*2+nt)*64+lane)*8+e]
//   per-tap k = (lane>>4)*8 + e ; real if k<18: c=k/6, j=k%6, f=c*9+tap
//   col n = lane&15 ; o = nt*16 + n
// ---------------------------------------------------------------------------
__global__ void kan_prepW(const float* __restrict__ bw, const float* __restrict__ sw,
                          const float* __restrict__ ss, _Float16* __restrict__ wb) {
    int t = blockIdx.x * 256 + threadIdx.x;
    if (t >= 9 * 2 * 64) return;
    const int lane = t & 63;
    const int nt = (t >> 6) & 1;
    const int tap = t >> 7;
    const int o = nt * 16 + (lane & 15);
    const int kbase = (lane >> 4) * 8;
    half8 v8 = {0, 0, 0, 0, 0, 0, 0, 0};
#pragma unroll
    for (int e = 0; e < 8; ++e) {
        int kk = kbase + e;
        float v = 0.0f;
        if (kk < 18) {
            int c = kk / 6, j = kk % 6;
            int f = c * 9 + tap;
            int of = o * IN_FEAT + f;
            v = (j == 0) ? bw[of] : sw[of * NB + (j - 1)] * ss[of];
        }
        v8[e] = (_Float16)v;
    }
    *(half8*)(wb + (size_t)t * 8) = v8;
}

// ---------------------------------------------------------------------------
// Fused kernel: block = 256 thr = 4 waves = 64 consecutive pixels of one row.
//  Phase 1: threads 0..197 compute phi for the 3x66 halo records into LDS
//           (OOB pixels -> x=0 -> phi(0), = reference zero-pad semantics).
//  Phase 2: each wave: 16-pixel M-tile, 9 taps x 2 N-tiles -> 18 MFMA,
//           A-fragments straight from LDS, B-fragments from LDS weights.
//  Phase 3: transpose via LDS (aliased over phi tile), coalesced stores.
// ---------------------------------------------------------------------------
__global__ __launch_bounds__(256) void kan_fused(const float* __restrict__ x,
                                                 const float* __restrict__ grid,
                                                 const _Float16* __restrict__ wb,
                                                 float* __restrict__ out) {
    __shared__ _Float16 lW[WB_HALVES];    // 18432 B
    __shared__ f32x4 lBuf[594];           // 9504 B: phi tile, then output transpose

    const int tid = threadIdx.x;
    // weights -> LDS (L2-resident source)
    for (int i = tid; i < WB_HALVES / 8; i += 256)
        ((u32x4*)lW)[i] = ((const u32x4*)wb)[i];

    const int p0 = blockIdx.x * 64;
    const int b = p0 >> 16;
    const int h = (p0 >> 8) & (HH - 1);
    const int w0 = p0 & (WW - 1);

    // ---- Phase 1: phi halo tile ----
    _Float16* lPhi = (_Float16*)lBuf;
    if (tid < NREC) {
        const int dyR = tid / TW;            // 0..2
        const int wxR = tid % TW - 1;        // -1..64
        const int hy = h + dyR - 1;
        const int wx = w0 + wxR;
        const bool vld = (hy >= 0) & (hy < HH) & (wx >= 0) & (wx < WW);

        float g[NG], r1[NG - 1], r2[NG - 2];
        load_grid(grid, g, r1, r2);

        _Float16 rec[RECE];
#pragma unroll
        for (int c = 0; c < IN_CH; ++c) {
            const float xx = vld ? x[((b * IN_CH + c) << 16) + (hy << 8) + wx] : 0.0f;
            float o6[6];
            kan_phi6(xx, g, r1, r2, o6);
#pragma unroll
            for (int j = 0; j < 6; ++j) rec[c * 6 + j] = (_Float16)o6[j];
        }
#pragma unroll
        for (int j = 18; j < RECE; ++j) rec[j] = (_Float16)0.0f;

        half8* dst = (half8*)(lPhi + tid * RECE);
        dst[0] = *(half8*)(rec + 0);
        dst[1] = *(half8*)(rec + 8);
        dst[2] = *(half8*)(rec + 16);
    }
    __syncthreads();

    // ---- Phase 2: MFMA ----
    const int lane = tid & 63;
    const int wid = tid >> 6;
    const int r = lane & 15;      // A row (pixel) / B col within tile
    const int gq = lane >> 4;     // k-group (0..3); gq==3 -> zero pad

    half8 af[9];
#pragma unroll
    for (int dy = 0; dy < 3; ++dy) {
#pragma unroll
        for (int dx = 0; dx < 3; ++dx) {
            const int tR = dy * TW + wid * 16 + r + dx;   // halo record index
            half8 v = {0, 0, 0, 0, 0, 0, 0, 0};
            if (gq < 3) v = *(const half8*)(lPhi + tR * RECE + gq * 8);
            af[dy * 3 + dx] = v;
        }
    }

    f32x4 acc0 = {0.f, 0.f, 0.f, 0.f};
    f32x4 acc1 = {0.f, 0.f, 0.f, 0.f};
    const half8* lw8 = (const half8*)lW;
#pragma unroll
    for (int tap = 0; tap < 9; ++tap) {
        half8 bf0 = lw8[(tap * 2 + 0) * 64 + lane];
        half8 bf1 = lw8[(tap * 2 + 1) * 64 + lane];
        acc0 = __builtin_amdgcn_mfma_f32_16x16x32_f16(af[tap], bf0, acc0, 0, 0, 0);
        acc1 = __builtin_amdgcn_mfma_f32_16x16x32_f16(af[tap], bf1, acc1, 0, 0, 0);
    }
    __syncthreads();   // all lPhi reads done; lBuf may be reused as lO

    // ---- Phase 3: transpose + coalesced store ----
    float* lO = (float*)lBuf;      // 64 x 33 floats = 8448 B
#pragma unroll
    for (int i = 0; i < 4; ++i) {
        lO[(wid * 16 + gq * 4 + i) * 33 + r] = acc0[i];
        lO[(wid * 16 + gq * 4 + i) * 33 + 16 + r] = acc1[i];
    }
    __syncthreads();

    const int o = tid >> 3;
    const int ps = (tid & 7) * 8;
    float v[8];
#pragma unroll
    for (int i = 0; i < 8; ++i) v[i] = lO[(ps + i) * 33 + o];
    float* op = out + (((size_t)(b * OUT_CH + o) << 8) + h) * WW + w0 + ps;
    *(f32x4*)op       = (f32x4){v[0], v[1], v[2], v[3]};
    *(f32x4*)(op + 4) = (f32x4){v[4], v[5], v[6], v[7]};
}

// ===========================================================================
// Fallback (round-1 fp32 path) if ws_size is too small for wb
// ===========================================================================
__global__ void kan_combine_weights(const float* __restrict__ bw,
                                    const float* __restrict__ sw,
                                    const float* __restrict__ ss,
                                    float* __restrict__ wc) {
    int idx = blockIdx.x * blockDim.x + threadIdx.x;
    if (idx >= IN_FEAT * 6 * OUT_CH) return;
    int o = idx & 31;
    int j = (idx >> 5) % 6;
    int f = idx / (6 * 32);
    float v;
    if (j == 0) v = bw[o * IN_FEAT + f];
    else        v = sw[(o * IN_FEAT + f) * NB + (j - 1)] * ss[o * IN_FEAT + f];
    wc[idx] = v;
}

__global__ __launch_bounds__(256) void kan_main(const float* __restrict__ x,
                                                const float* __restrict__ grid,
                                                const float* __restrict__ wc,
                                                float* __restrict__ out) {
    const int p = blockIdx.x * blockDim.x + threadIdx.x;
    const int w = p & (WW - 1);
    const int h = (p >> 8) & (HH - 1);
    const int b = p >> 16;
    float g[NG], r1[NG - 1], r2[NG - 2];
    load_grid(grid, g, r1, r2);
    float acc[OUT_CH];
#pragma unroll
    for (int o = 0; o < OUT_CH; ++o) acc[o] = 0.0f;
    const float* xb = x + b * (IN_CH * HH * WW);
    for (int c = 0; c < IN_CH; ++c) {
        const float* xc = xb + c * (HH * WW);
#pragma unroll
        for (int dy = 0; dy < 3; ++dy) {
            const int hy = h + dy - 1;
            const bool vy = (hy >= 0) && (hy < HH);
#pragma unroll
            for (int dx = 0; dx < 3; ++dx) {
                const int wx = w + dx - 1;
                const bool vld = vy && (wx >= 0) && (wx < WW);
                const float xx = vld ? xc[hy * WW + wx] : 0.0f;
                float o6[6];
                kan_phi6(xx, g, r1, r2, o6);
                const float* wf = wc + (c * 9 + dy * 3 + dx) * (6 * OUT_CH);
#pragma unroll
                for (int jj = 0; jj < 6; ++jj) {
                    const float* wj = wf + jj * OUT_CH;
#pragma unroll
                    for (int o = 0; o < OUT_CH; ++o) acc[o] += o6[jj] * wj[o];
                }
            }
        }
    }
    float* ob = out + (size_t)b * (OUT_CH * HH * WW) + h * WW + w;
#pragma unroll
    for (int o = 0; o < OUT_CH; ++o) ob[o * (HH * WW)] = acc[o];
}

// ===========================================================================
extern "C" void kernel_launch(void* const* d_in, const int* in_sizes, int n_in,
                              void* d_out, int out_size, void* d_ws, size_t ws_size,
                              hipStream_t stream) {
    const float* x    = (const float*)d_in[0];
    const float* bw   = (const float*)d_in[1];
    const float* sw   = (const float*)d_in[2];
    const float* ss   = (const float*)d_in[3];
    const float* grid = (const float*)d_in[4];
    float* out = (float*)d_out;

    if (ws_size >= WS_NEEDED) {
        _Float16* wb = (_Float16*)d_ws;
        kan_prepW<<<(9 * 2 * 64 + 255) / 256, 256, 0, stream>>>(bw, sw, ss, wb);
        kan_fused<<<NPIX / 64, 256, 0, stream>>>(x, grid, wb, out);
    } else {
        float* wc = (float*)d_ws;
        kan_combine_weights<<<(IN_FEAT * 6 * OUT_CH + 255) / 256, 256, 0, stream>>>(bw, sw, ss, wc);
        kan_main<<<NPIX / 256, 256, 0, stream>>>(x, grid, wc, out);
    }
}

// Round 6
// 47.533 us; speedup vs baseline: 9.3485x; 1.5143x over previous
//
#include <hip/hip_runtime.h>

#define IN_CH 3
#define OUT_CH 32
#define IN_FEAT 27
#define NB 5
#define NG 8
#define HH 256
#define WW 256
#define NPIX (16 * HH * WW)

// Phi record: 24 fp16 payload, padded to 28 halves (56 B) in LDS for bank spread
#define RECE 24
#define RECP 28
#define TW 66                            // halo tile width (64 + 2)
#define TROWS 6                          // halo rows (4 + 2)
#define NREC (TROWS * TW)                // 396 records per block
#define WB_HALVES (9 * 2 * 64 * 8)       // 9216 halves = 18432 B
#define GTAB_FLOATS 21                   // g[8], r1[7], r2[6]
#define WS_NEEDED ((size_t)WB_HALVES * 2 + GTAB_FLOATS * 4)

typedef __attribute__((ext_vector_type(8))) _Float16 half8;
typedef __attribute__((ext_vector_type(4))) float f32x4;
typedef __attribute__((ext_vector_type(4))) unsigned int u32x4;

// silu + quadratic B-spline bases (exact Cox-de Boor per reference)
__device__ inline void kan_phi6(float xx, const float* g, const float* r1, const float* r2,
                                float* o6) {
    const float sig = 1.0f / (1.0f + __expf(-xx));
    o6[0] = xx * sig;
    float b0[7];
#pragma unroll
    for (int j = 0; j < 7; ++j) b0[j] = (xx >= g[j] && xx < g[j + 1]) ? 1.0f : 0.0f;
    float b1[6];
#pragma unroll
    for (int j = 0; j < 6; ++j)
        b1[j] = (xx - g[j]) * r1[j] * b0[j] + (g[j + 2] - xx) * r1[j + 1] * b0[j + 1];
#pragma unroll
    for (int j = 0; j < NB; ++j)
        o6[1 + j] = (xx - g[j]) * r2[j] * b1[j] + (g[j + 3] - xx) * r2[j + 1] * b1[j + 1];
}

__device__ inline void load_grid(const float* __restrict__ grid, float* g, float* r1, float* r2) {
#pragma unroll
    for (int j = 0; j < NG; ++j) g[j] = grid[j];
#pragma unroll
    for (int j = 0; j < NG - 1; ++j) r1[j] = 1.0f / (g[j + 1] - g[j]);
#pragma unroll
    for (int j = 0; j < NG - 2; ++j) r2[j] = 1.0f / (g[j + 2] - g[j]);
}

// ---------------------------------------------------------------------------
// Prep: weights -> exact B-fragment layout (fp16). wb[((tap*2+nt)*64+lane)*8+e]
//   per-tap k = (lane>>4)*8 + e ; real if k<18: c=k/6, j=k%6, f=c*9+tap
//   col n = lane&15 ; o = nt*16 + n
// Thread 0 also writes the 21-float grid table (g, 1/d1, 1/d2) after wb.
// ---------------------------------------------------------------------------
__global__ void kan_prepW(const float* __restrict__ bw, const float* __restrict__ sw,
                          const float* __restrict__ ss, const float* __restrict__ grid,
                          _Float16* __restrict__ wb) {
    int t = blockIdx.x * 256 + threadIdx.x;
    if (t >= 9 * 2 * 64) return;

    if (t == 0) {
        float g[NG], r1[NG - 1], r2[NG - 2];
        load_grid(grid, g, r1, r2);
        float* gt = (float*)(wb + WB_HALVES);
#pragma unroll
        for (int j = 0; j < NG; ++j) gt[j] = g[j];
#pragma unroll
        for (int j = 0; j < NG - 1; ++j) gt[NG + j] = r1[j];
#pragma unroll
        for (int j = 0; j < NG - 2; ++j) gt[NG + NG - 1 + j] = r2[j];
    }

    const int lane = t & 63;
    const int nt = (t >> 6) & 1;
    const int tap = t >> 7;
    const int o = nt * 16 + (lane & 15);
    const int kbase = (lane >> 4) * 8;
    half8 v8 = {0, 0, 0, 0, 0, 0, 0, 0};
#pragma unroll
    for (int e = 0; e < 8; ++e) {
        int kk = kbase + e;
        float v = 0.0f;
        if (kk < 18) {
            int c = kk / 6, j = kk % 6;
            int f = c * 9 + tap;
            int of = o * IN_FEAT + f;
            v = (j == 0) ? bw[of] : sw[of * NB + (j - 1)] * ss[of];
        }
        v8[e] = (_Float16)v;
    }
    *(half8*)(wb + (size_t)t * 8) = v8;
}

// ---------------------------------------------------------------------------
// Fused kernel: block = 256 thr = 4 waves; tile = 64 wide x 4 rows = 256 pixels.
//  Phase 1: 396 halo records (6x66) -> LDS (OOB -> phi(0), = ref zero-pad).
//  Phase 2: wave wid owns row h0+wid: 4 M-tiles x 9 taps x 2 N -> 72 MFMA;
//           B-frags register-resident from global (L2); direct dwordx4 stores.
// ---------------------------------------------------------------------------
__global__ __launch_bounds__(256) void kan_fused(const float* __restrict__ x,
                                                 const _Float16* __restrict__ wb,
                                                 float* __restrict__ out) {
    __shared__ _Float16 lPhi[NREC * RECP];   // 22176 B

    const int tid = threadIdx.x;
    const int bid = blockIdx.x;
    const int strip = bid & 3;
    const int rowg = (bid >> 2) & 63;
    const int b = bid >> 8;
    const int h0 = rowg * 4;
    const int w0 = strip * 64;

    // ---- B-fragments: straight from global (L2-resident), once per thread ----
    const int lane = tid & 63;
    const int wid = tid >> 6;
    const int r = lane & 15;      // A row (pixel) / B col (channel) within tile
    const int gq = lane >> 4;     // k-group (0..3); gq==3 -> zero pad

    half8 bf[18];
#pragma unroll
    for (int i = 0; i < 18; ++i)
        bf[i] = *(const half8*)(wb + ((size_t)(i * 64 + lane)) * 8);

    // ---- Phase 1: phi halo tile ----
    const float* gt = (const float*)(wb + WB_HALVES);
    float g[NG], r1[NG - 1], r2[NG - 2];
#pragma unroll
    for (int j = 0; j < NG; ++j) g[j] = gt[j];
#pragma unroll
    for (int j = 0; j < NG - 1; ++j) r1[j] = gt[NG + j];
#pragma unroll
    for (int j = 0; j < NG - 2; ++j) r2[j] = gt[NG + NG - 1 + j];

    for (int rr = tid; rr < NREC; rr += 256) {
        const int dyR = rr / TW;             // 0..5
        const int wxR = rr - dyR * TW - 1;   // -1..64
        const int hy = h0 + dyR - 1;
        const int wx = w0 + wxR;
        const bool vld = ((unsigned)hy < HH) & ((unsigned)wx < WW);

        _Float16 rec[RECE];
#pragma unroll
        for (int c = 0; c < IN_CH; ++c) {
            const float xx = vld ? x[((b * IN_CH + c) << 16) + (hy << 8) + wx] : 0.0f;
            float o6[6];
            kan_phi6(xx, g, r1, r2, o6);
#pragma unroll
            for (int j = 0; j < 6; ++j) rec[c * 6 + j] = (_Float16)o6[j];
        }
#pragma unroll
        for (int j = 18; j < RECE; ++j) rec[j] = (_Float16)0.0f;

        half8* dst = (half8*)(lPhi + rr * RECP);
        dst[0] = *(half8*)(rec + 0);
        dst[1] = *(half8*)(rec + 8);
        dst[2] = *(half8*)(rec + 16);
    }
    __syncthreads();

    // ---- Phase 2: 4 M-tiles along the wave's row ----
    const int hrow = h0 + wid;
#pragma unroll
    for (int m = 0; m < 4; ++m) {
        half8 af[9];
#pragma unroll
        for (int dy = 0; dy < 3; ++dy) {
#pragma unroll
            for (int dx = 0; dx < 3; ++dx) {
                const int rec = (wid + dy) * TW + m * 16 + r + dx;
                half8 v = {0, 0, 0, 0, 0, 0, 0, 0};
                if (gq < 3) v = *(const half8*)(lPhi + rec * RECP + gq * 8);
                af[dy * 3 + dx] = v;
            }
        }

        f32x4 acc0 = {0.f, 0.f, 0.f, 0.f};
        f32x4 acc1 = {0.f, 0.f, 0.f, 0.f};
#pragma unroll
        for (int tap = 0; tap < 9; ++tap) {
            acc0 = __builtin_amdgcn_mfma_f32_16x16x32_f16(af[tap], bf[tap * 2 + 0], acc0, 0, 0, 0);
            acc1 = __builtin_amdgcn_mfma_f32_16x16x32_f16(af[tap], bf[tap * 2 + 1], acc1, 0, 0, 0);
        }

        // Direct stores: lane holds 4 consecutive-w pixels for channel r / r+16
        const int wcol = w0 + m * 16 + gq * 4;
        float* op0 = out + ((size_t)(b * OUT_CH + r) << 16) + (hrow << 8) + wcol;
        float* op1 = out + ((size_t)(b * OUT_CH + 16 + r) << 16) + (hrow << 8) + wcol;
        *(f32x4*)op0 = acc0;
        *(f32x4*)op1 = acc1;
    }
}

// ===========================================================================
// Fallback (round-1 fp32 path) if ws_size is too small for wb
// ===========================================================================
__global__ void kan_combine_weights(const float* __restrict__ bw,
                                    const float* __restrict__ sw,
                                    const float* __restrict__ ss,
                                    float* __restrict__ wc) {
    int idx = blockIdx.x * blockDim.x + threadIdx.x;
    if (idx >= IN_FEAT * 6 * OUT_CH) return;
    int o = idx & 31;
    int j = (idx >> 5) % 6;
    int f = idx / (6 * 32);
    float v;
    if (j == 0) v = bw[o * IN_FEAT + f];
    else        v = sw[(o * IN_FEAT + f) * NB + (j - 1)] * ss[o * IN_FEAT + f];
    wc[idx] = v;
}

__global__ __launch_bounds__(256) void kan_main(const float* __restrict__ x,
                                                const float* __restrict__ grid,
                                                const float* __restrict__ wc,
                                                float* __restrict__ out) {
    const int p = blockIdx.x * blockDim.x + threadIdx.x;
    const int w = p & (WW - 1);
    const int h = (p >> 8) & (HH - 1);
    const int b = p >> 16;
    float g[NG], r1[NG - 1], r2[NG - 2];
    load_grid(grid, g, r1, r2);
    float acc[OUT_CH];
#pragma unroll
    for (int o = 0; o < OUT_CH; ++o) acc[o] = 0.0f;
    const float* xb = x + b * (IN_CH * HH * WW);
    for (int c = 0; c < IN_CH; ++c) {
        const float* xc = xb + c * (HH * WW);
#pragma unroll
        for (int dy = 0; dy < 3; ++dy) {
            const int hy = h + dy - 1;
            const bool vy = (hy >= 0) && (hy < HH);
#pragma unroll
            for (int dx = 0; dx < 3; ++dx) {
                const int wx = w + dx - 1;
                const bool vld = vy && (wx >= 0) && (wx < WW);
                const float xx = vld ? xc[hy * WW + wx] : 0.0f;
                float o6[6];
                kan_phi6(xx, g, r1, r2, o6);
                const float* wf = wc + (c * 9 + dy * 3 + dx) * (6 * OUT_CH);
#pragma unroll
                for (int jj = 0; jj < 6; ++jj) {
                    const float* wj = wf + jj * OUT_CH;
#pragma unroll
                    for (int o = 0; o < OUT_CH; ++o) acc[o] += o6[jj] * wj[o];
                }
            }
        }
    }
    float* ob = out + (size_t)b * (OUT_CH * HH * WW) + h * WW + w;
#pragma unroll
    for (int o = 0; o < OUT_CH; ++o) ob[o * (HH * WW)] = acc[o];
}

// ===========================================================================
extern "C" void kernel_launch(void* const* d_in, const int* in_sizes, int n_in,
                              void* d_out, int out_size, void* d_ws, size_t ws_size,
                              hipStream_t stream) {
    const float* x    = (const float*)d_in[0];
    const float* bw   = (const float*)d_in[1];
    const float* sw   = (const float*)d_in[2];
    const float* ss   = (const float*)d_in[3];
    const float* grid = (const float*)d_in[4];
    float* out = (float*)d_out;

    if (ws_size >= WS_NEEDED) {
        _Float16* wb = (_Float16*)d_ws;
        kan_prepW<<<(9 * 2 * 64 + 255) / 256, 256, 0, stream>>>(bw, sw, ss, grid, wb);
        kan_fused<<<NPIX / 256, 256, 0, stream>>>(x, wb, out);
    } else {
        float* wc = (float*)d_ws;
        kan_combine_weights<<<(IN_FEAT * 6 * OUT_CH + 255) / 256, 256, 0, stream>>>(bw, sw, ss, wc);
        kan_main<<<NPIX / 256, 256, 0, stream>>>(x, grid, wc, out);
    }
}